// Round 2
// baseline (430.442 us; speedup 1.0000x reference)
//
#include <hip/hip_runtime.h>
#include <math.h>

#define B 64
#define T 2000
#define E 512
#define R 1024
#define A 512
#define M 8

#define NCH 16          // t-chunks for context kernel
#define TCH (T / NCH)   // 125
#define NP  (NCH * 4)   // partials per batch (4 tp-groups per chunk)

typedef float nfloat4 __attribute__((ext_vector_type(4)));  // native vec for nontemporal builtin

// ---------------------------------------------------------------------------
// Cross-kernel scratch lives in static device globals, NOT in d_ws.
// Rationale: the harness re-poisons the full 1000 MiB workspace every timed
// iteration (~157 us fillBufferAligned dispatches dominate the window). These
// buffers are fully written before being read within every kernel_launch, so
// there is no stale-state dependence; d_ws is left completely untouched.
// ---------------------------------------------------------------------------
__device__ float g_params[B * 24];        // {wmix[8], loc[8], scale[8]} per b
__device__ float g_partials[B * NP * E];  // 8 MB partial contexts
__device__ float g_psum[B * NCH];         // per-chunk exp sums

__device__ __forceinline__ float sigmoidf_(float x) { return 1.0f / (1.0f + expf(-x)); }
__device__ __forceinline__ float dot4_(float4 a, float4 b) {
    return (a.x * b.x + a.y * b.y) + (a.z * b.z + a.w * b.w);
}

// ---------------------------------------------------------------------------
// K1: per-batch MLP head. One block (512 thr) per b. Wave-per-output GEMV:
// lanes span k (coalesced weight rows), activations in registers,
// shuffle-reduce per output. Writes g_params and out_loc.
// ---------------------------------------------------------------------------
__global__ __launch_bounds__(512) void mlp_kernel(
    const float* __restrict__ ahs, const float* __restrict__ prev_loc,
    const float* __restrict__ W1, const float* __restrict__ b1,
    const float* __restrict__ W2, const float* __restrict__ Wlin,
    const float* __restrict__ blin,
    float* __restrict__ out_loc)  // [B][M]
{
    __shared__ float sh_h[R];
    __shared__ float sh_t[A];
    __shared__ float sh_x[A];
    __shared__ float sh_y[3 * M];

    const int b = blockIdx.x;
    const int tid = threadIdx.x;
    const int wave = tid >> 6;
    const int lane = tid & 63;

    // h = tanh(ahs[b, :])
    for (int k = tid; k < R; k += 512) sh_h[k] = tanhf(ahs[b * R + k]);
    __syncthreads();

    // ---- layer 1: t[j] = h . W1[j,:] + b1[j]; wave handles j in [64w,64w+64)
    {
        const float4* h4 = (const float4*)sh_h;
        const float4 h0 = h4[lane], h1 = h4[lane + 64],
                     h2 = h4[lane + 128], h3 = h4[lane + 192];
        for (int j = 0; j < 64; j += 2) {
            const int ja = wave * 64 + j;
            const int jb = ja + 1;
            const float4* ra = (const float4*)(W1 + (size_t)ja * R);
            const float4* rb = (const float4*)(W1 + (size_t)jb * R);
            float4 a0 = ra[lane], a1 = ra[lane + 64], a2 = ra[lane + 128], a3 = ra[lane + 192];
            float4 c0 = rb[lane], c1 = rb[lane + 64], c2 = rb[lane + 128], c3 = rb[lane + 192];
            float accA = (dot4_(h0, a0) + dot4_(h1, a1)) + (dot4_(h2, a2) + dot4_(h3, a3));
            float accB = (dot4_(h0, c0) + dot4_(h1, c1)) + (dot4_(h2, c2) + dot4_(h3, c3));
#pragma unroll
            for (int off = 32; off > 0; off >>= 1) {
                accA += __shfl_down(accA, off);
                accB += __shfl_down(accB, off);
            }
            if (lane == 0) {
                sh_t[ja] = accA + b1[ja];
                sh_t[jb] = accB + b1[jb];
            }
        }
    }
    __syncthreads();

    // ---- layer 2: x[j] = tanh( t . W2[j,:] )
    {
        const float4* t4 = (const float4*)sh_t;
        const float4 t0 = t4[lane], t1 = t4[lane + 64];
        for (int j = 0; j < 64; j += 2) {
            const int ja = wave * 64 + j;
            const int jb = ja + 1;
            const float4* ra = (const float4*)(W2 + (size_t)ja * A);
            const float4* rb = (const float4*)(W2 + (size_t)jb * A);
            float4 a0 = ra[lane], a1 = ra[lane + 64];
            float4 c0 = rb[lane], c1 = rb[lane + 64];
            float accA = dot4_(t0, a0) + dot4_(t1, a1);
            float accB = dot4_(t0, c0) + dot4_(t1, c1);
#pragma unroll
            for (int off = 32; off > 0; off >>= 1) {
                accA += __shfl_down(accA, off);
                accB += __shfl_down(accB, off);
            }
            if (lane == 0) {
                sh_x[ja] = tanhf(accA);
                sh_x[jb] = tanhf(accB);
            }
        }
    }
    __syncthreads();

    // ---- head: y[i] = x . Wlin[i,:] + blin[i], 24 outputs, 16 threads each
    if (tid < 16 * 3 * M) {
        const int i = tid >> 4;
        const int l16 = tid & 15;
        float s = 0.f;
        for (int k = l16; k < A; k += 16) s += sh_x[k] * Wlin[i * A + k];
        s += __shfl_down(s, 8, 16);
        s += __shfl_down(s, 4, 16);
        s += __shfl_down(s, 2, 16);
        s += __shfl_down(s, 1, 16);
        if (l16 == 0) sh_y[i] = s + blin[i];
    }
    __syncthreads();

    if (tid < M) {
        const int m = tid;
        const float delta = sigmoidf_(sh_y[M + m]);
        const float loc = prev_loc[b * M + m] + delta;
        const float wmix = sigmoidf_(sh_y[m]);
        const float scale = sigmoidf_(sh_y[2 * M + m]) * 2.0f + 1.0f;
        out_loc[b * M + m] = loc;
        g_params[b * 24 + m]      = wmix;
        g_params[b * 24 + 8 + m]  = loc;
        g_params[b * 24 + 16 + m] = scale;
    }
}

// ---------------------------------------------------------------------------
// K2: fused alignment + exp + partial context. Grid (B, NCH), 512 threads.
// Normalize-late: ctx = (sum_t e_t * mem_t) / (sum_t e_t). 125 threads
// compute e_t for the chunk (hidden under the HBM stream), all 512 then
// stream memory read-once with nontemporal loads. Writes unnormalized e_t to
// out_w (normalized in K3), per-chunk exp sums to g_psum, 4 tp partials.
// ---------------------------------------------------------------------------
__global__ __launch_bounds__(512) void context_align_kernel(
    const float* __restrict__ memory,
    const unsigned char* __restrict__ mask,
    float* __restrict__ out_w)           // [B][T] (unnormalized exp)
{
    __shared__ float sh_w[TCH];
    __shared__ float sh_p[24];

    const int b = blockIdx.x;
    const int chunk = blockIdx.y;
    const int tid = threadIdx.x;
    const int t0 = chunk * TCH;

    if (tid < 24) sh_p[tid] = g_params[b * 24 + tid];
    __syncthreads();

    // alignment -> exp for this chunk's 125 t values. a[t] in [0, M) since
    // z>=0, wmix<1, so exp is safe without max-subtraction (softmax is
    // shift-invariant; context normalization divides it out).
    if (tid < TCH) {
        const int t = t0 + tid;
        const float tf = (float)t;
        float v = 0.f;
#pragma unroll
        for (int m = 0; m < M; ++m) {
            const float d = sh_p[8 + m] - tf;
            const float s = sh_p[16 + m];
            v += 0.5f * (erff((d + 0.5f) * s) - erff((d - 0.5f) * s)) * sh_p[m];
        }
        if (mask[b * T + t]) v = 0.f;
        const float e = expf(v);
        sh_w[tid] = e;
        out_w[b * T + t] = e;
    }
    __syncthreads();

    // per-chunk exp sum (one wave; overlaps with other waves' streaming)
    if (tid < 64) {
        float s = 0.f;
        for (int k = tid; k < TCH; k += 64) s += sh_w[k];
#pragma unroll
        for (int off = 32; off > 0; off >>= 1) s += __shfl_down(s, off);
        if (tid == 0) g_psum[b * NCH + chunk] = s;
    }

    // streaming: e4 = tid&127 covers E as float4; tp = tid>>7 gives 4
    // t-streams, each writing its own partial. memory read-once -> nontemporal.
    const int e4 = tid & 127;
    const int tp = tid >> 7;  // 0..3
    const nfloat4* mem4 = (const nfloat4*)(memory + (size_t)(b * T + t0) * E);

    float acc0 = 0.f, acc1 = 0.f, acc2 = 0.f, acc3 = 0.f;
#pragma unroll 4
    for (int t = tp; t < TCH; t += 4) {
        const float wv = sh_w[t];
        const nfloat4 mv = __builtin_nontemporal_load(&mem4[(size_t)t * (E / 4) + e4]);
        acc0 += wv * mv.x;
        acc1 += wv * mv.y;
        acc2 += wv * mv.z;
        acc3 += wv * mv.w;
    }

    nfloat4 accv = {acc0, acc1, acc2, acc3};
    nfloat4* dst = (nfloat4*)(g_partials + (((size_t)b * NCH + chunk) * 4 + tp) * E);
    dst[e4] = accv;
}

// ---------------------------------------------------------------------------
// K3: per-batch finalize. Grid B, 256 threads.
// total_b = sum(psum[b,:]); ctx[b] = (sum partials[b]) / total; w[b] /= total.
// ---------------------------------------------------------------------------
__global__ __launch_bounds__(256) void finalize_kernel(
    float* __restrict__ out_ctx,         // [B][E]
    float* __restrict__ out_w)           // [B][T], in-place normalize
{
    __shared__ float s_inv;
    const int b = blockIdx.x;
    const int tid = threadIdx.x;

    if (tid < 64) {
        float s = (tid < NCH) ? g_psum[b * NCH + tid] : 0.f;
#pragma unroll
        for (int off = 32; off > 0; off >>= 1) s += __shfl_down(s, off);
        if (tid == 0) s_inv = 1.0f / s;
    }
    __syncthreads();
    const float inv = s_inv;

    // context reduce: E/4 = 128 float4 lanes
    if (tid < E / 4) {
        const float4* p = (const float4*)g_partials + (size_t)b * NP * (E / 4) + tid;
        float4 acc = {0.f, 0.f, 0.f, 0.f};
#pragma unroll 8
        for (int c = 0; c < NP; ++c) {
            const float4 v = p[(size_t)c * (E / 4)];
            acc.x += v.x; acc.y += v.y; acc.z += v.z; acc.w += v.w;
        }
        float4 r = {acc.x * inv, acc.y * inv, acc.z * inv, acc.w * inv};
        ((float4*)out_ctx)[b * (E / 4) + tid] = r;
    }

    // normalize attention weights in place (T/4 = 500 float4 per b)
    float4* w4 = (float4*)(out_w + (size_t)b * T);
    for (int i = tid; i < T / 4; i += 256) {
        float4 v = w4[i];
        v.x *= inv; v.y *= inv; v.z *= inv; v.w *= inv;
        w4[i] = v;
    }
}

extern "C" void kernel_launch(void* const* d_in, const int* in_sizes, int n_in,
                              void* d_out, int out_size, void* d_ws, size_t ws_size,
                              hipStream_t stream) {
    const float* ahs      = (const float*)d_in[0];
    const float* memory   = (const float*)d_in[1];
    const float* prev_loc = (const float*)d_in[2];
    const unsigned char* mask = (const unsigned char*)d_in[3];
    const float* W1   = (const float*)d_in[4];
    const float* b1   = (const float*)d_in[5];
    const float* W2   = (const float*)d_in[6];
    const float* Wlin = (const float*)d_in[7];
    const float* blin = (const float*)d_in[8];

    float* out = (float*)d_out;
    float* out_ctx = out;                    // [B][E]
    float* out_w   = out + B * E;            // [B][T]
    float* out_loc = out + B * E + B * T;    // [B][M]

    // d_ws intentionally unused: all scratch is in static __device__ globals
    // (fully rewritten before read within this launch), so the harness's
    // 1000 MiB workspace re-poison has nothing of ours to protect.
    (void)d_ws; (void)ws_size;

    mlp_kernel<<<dim3(B), dim3(512), 0, stream>>>(
        ahs, prev_loc, W1, b1, W2, Wlin, blin, out_loc);

    context_align_kernel<<<dim3(B, NCH), dim3(512), 0, stream>>>(
        memory, mask, out_w);

    finalize_kernel<<<dim3(B), dim3(256), 0, stream>>>(out_ctx, out_w);
}

// Round 3
// 409.456 us; speedup vs baseline: 1.0513x; 1.0513x over previous
//
#include <hip/hip_runtime.h>
#include <math.h>

#define B 64
#define T 2000
#define E 512
#define R 1024
#define A 512
#define M 8

#define NCH 16          // t-chunks for stream blocks
#define TCH (T / NCH)   // 125
#define NP  (NCH * 4)   // partials per batch (4 tp-groups per chunk)

typedef float nfloat4 __attribute__((ext_vector_type(4)));  // native vec for nontemporal builtin

// ---------------------------------------------------------------------------
// Cross-kernel scratch in static device globals (d_ws untouched; the harness
// re-poisons the 1000 MiB workspace unconditionally, ~157us fills — proven
// rounds 1-2). All buffers fully written before read within each launch.
// ---------------------------------------------------------------------------
__device__ float g_partials[B * NP * E];  // 8 MB unweighted-sum partials
__device__ float g_corr[B * E];           // near-field correction Sum (e_t-1)*mem_t
__device__ float g_zinv[B];               // 1 / Z
__device__ int   g_tcut[B];               // far-field cutoff per batch

__device__ __forceinline__ float sigmoidf_(float x) { return 1.0f / (1.0f + expf(-x)); }
__device__ __forceinline__ float dot4_(float4 a, float4 b) {
    return (a.x * b.x + a.y * b.y) + (a.z * b.z + a.w * b.w);
}

// ---------------------------------------------------------------------------
// K1: fused kernel, grid = B (MLP blocks, dispatched first) + B*NCH (stream).
//
// KEY IDENTITY: for t >= loc_m + 0.5 + 8/scale_m (all m), both erff args are
// <= -8 where fp32 erff returns exactly -1.0, so the alignment v is exactly
// 0.0 and e^v is exactly 1.0 (masked entries also give v=0 -> e=1). Hence
//   ctx*Z = Sum_t mem_t  +  Sum_{t<tcut} (e_t - 1)*mem_t,   w_{t>=tcut} = 1/Z.
// The big 262 MB stream is therefore an UNWEIGHTED sum, independent of the
// MLP -> both run concurrently in this one launch; the MLP + near-field
// correction (~2 MB of mem reads) hides entirely under the HBM stream.
// tcut is computed dynamically from loc/scale (generic fallback up to T).
// ---------------------------------------------------------------------------
__global__ __launch_bounds__(512, 4) void fused_kernel(
    const float* __restrict__ ahs, const float* __restrict__ prev_loc,
    const unsigned char* __restrict__ mask,
    const float* __restrict__ W1, const float* __restrict__ b1,
    const float* __restrict__ W2, const float* __restrict__ Wlin,
    const float* __restrict__ blin,
    const float* __restrict__ memory,
    float* __restrict__ out_w,    // [B][T]: e_t written for t<tcut (unnormalized)
    float* __restrict__ out_loc)  // [B][M]
{
    const int tid = threadIdx.x;

    if (blockIdx.x >= B) {
        // ---- stream path: unweighted partial sum of memory over a t-chunk
        const int sblk = blockIdx.x - B;
        const int b = sblk / NCH;
        const int chunk = sblk - b * NCH;
        const int e4 = tid & 127;
        const int tp = tid >> 7;  // 0..3
        const nfloat4* mem4 = (const nfloat4*)(memory + (size_t)(b * T + chunk * TCH) * E);

        float acc0 = 0.f, acc1 = 0.f, acc2 = 0.f, acc3 = 0.f;
#pragma unroll 4
        for (int t = tp; t < TCH; t += 4) {
            const nfloat4 mv = __builtin_nontemporal_load(&mem4[(size_t)t * (E / 4) + e4]);
            acc0 += mv.x; acc1 += mv.y; acc2 += mv.z; acc3 += mv.w;
        }
        nfloat4 accv = {acc0, acc1, acc2, acc3};
        nfloat4* dst = (nfloat4*)(g_partials + (((size_t)b * NCH + chunk) * 4 + tp) * E);
        dst[e4] = accv;
        return;
    }

    // ---- MLP path: one block per b
    __shared__ float sh_h[R];
    __shared__ float sh_t[A];
    __shared__ float sh_x[A];
    __shared__ float sh_y[3 * M];
    __shared__ float sh_loc[M], sh_scale[M], sh_wmix[M], sh_tc[M];
    __shared__ float sh_e[2048];
    __shared__ int sh_tcut;

    const int b = blockIdx.x;
    const int wave = tid >> 6;
    const int lane = tid & 63;

    // h = tanh(ahs[b, :])
    for (int k = tid; k < R; k += 512) sh_h[k] = tanhf(ahs[b * R + k]);
    __syncthreads();

    // ---- layer 1: t[j] = h . W1[j,:] + b1[j]; wave handles j in [64w,64w+64)
    {
        const float4* h4 = (const float4*)sh_h;
        const float4 h0 = h4[lane], h1 = h4[lane + 64],
                     h2 = h4[lane + 128], h3 = h4[lane + 192];
        for (int j = 0; j < 64; j += 2) {
            const int ja = wave * 64 + j;
            const int jb = ja + 1;
            const float4* ra = (const float4*)(W1 + (size_t)ja * R);
            const float4* rb = (const float4*)(W1 + (size_t)jb * R);
            float4 a0 = ra[lane], a1 = ra[lane + 64], a2 = ra[lane + 128], a3 = ra[lane + 192];
            float4 c0 = rb[lane], c1 = rb[lane + 64], c2 = rb[lane + 128], c3 = rb[lane + 192];
            float accA = (dot4_(h0, a0) + dot4_(h1, a1)) + (dot4_(h2, a2) + dot4_(h3, a3));
            float accB = (dot4_(h0, c0) + dot4_(h1, c1)) + (dot4_(h2, c2) + dot4_(h3, c3));
#pragma unroll
            for (int off = 32; off > 0; off >>= 1) {
                accA += __shfl_down(accA, off);
                accB += __shfl_down(accB, off);
            }
            if (lane == 0) {
                sh_t[ja] = accA + b1[ja];
                sh_t[jb] = accB + b1[jb];
            }
        }
    }
    __syncthreads();

    // ---- layer 2: x[j] = tanh( t . W2[j,:] )
    {
        const float4* t4 = (const float4*)sh_t;
        const float4 t0 = t4[lane], t1 = t4[lane + 64];
        for (int j = 0; j < 64; j += 2) {
            const int ja = wave * 64 + j;
            const int jb = ja + 1;
            const float4* ra = (const float4*)(W2 + (size_t)ja * A);
            const float4* rb = (const float4*)(W2 + (size_t)jb * A);
            float4 a0 = ra[lane], a1 = ra[lane + 64];
            float4 c0 = rb[lane], c1 = rb[lane + 64];
            float accA = dot4_(t0, a0) + dot4_(t1, a1);
            float accB = dot4_(t0, c0) + dot4_(t1, c1);
#pragma unroll
            for (int off = 32; off > 0; off >>= 1) {
                accA += __shfl_down(accA, off);
                accB += __shfl_down(accB, off);
            }
            if (lane == 0) {
                sh_x[ja] = tanhf(accA);
                sh_x[jb] = tanhf(accB);
            }
        }
    }
    __syncthreads();

    // ---- head: y[i] = x . Wlin[i,:] + blin[i], 24 outputs, 16 threads each
    if (tid < 16 * 3 * M) {
        const int i = tid >> 4;
        const int l16 = tid & 15;
        float s = 0.f;
        for (int k = l16; k < A; k += 16) s += sh_x[k] * Wlin[i * A + k];
        s += __shfl_down(s, 8, 16);
        s += __shfl_down(s, 4, 16);
        s += __shfl_down(s, 2, 16);
        s += __shfl_down(s, 1, 16);
        if (l16 == 0) sh_y[i] = s + blin[i];
    }
    __syncthreads();

    if (tid < M) {
        const int m = tid;
        const float delta = sigmoidf_(sh_y[M + m]);
        const float loc = prev_loc[b * M + m] + delta;
        const float scale = sigmoidf_(sh_y[2 * M + m]) * 2.0f + 1.0f;
        sh_wmix[m]  = sigmoidf_(sh_y[m]);
        sh_loc[m]   = loc;
        sh_scale[m] = scale;
        sh_tc[m]    = loc + 0.5f + 8.0f / scale;  // erff saturation cutoff, margin 8
        out_loc[b * M + m] = loc;
    }
    __syncthreads();

    if (tid == 0) {
        float mx = sh_tc[0];
        for (int m = 1; m < M; ++m) mx = fmaxf(mx, sh_tc[m]);
        int tc = (int)ceilf(mx);
        if (tc < 0) tc = 0;
        if (tc > T) tc = T;
        sh_tcut = tc;
        g_tcut[b] = tc;
    }
    __syncthreads();
    const int tcut = sh_tcut;

    // near-field e_t for t < tcut (expected tcut <= 20; generic up to T)
    for (int t = tid; t < tcut; t += 512) {
        const float tf = (float)t;
        float v = 0.f;
#pragma unroll
        for (int m = 0; m < M; ++m) {
            const float d = sh_loc[m] - tf;
            const float s = sh_scale[m];
            v += 0.5f * (erff((d + 0.5f) * s) - erff((d - 0.5f) * s)) * sh_wmix[m];
        }
        if (mask[b * T + t]) v = 0.f;
        const float e = expf(v);
        sh_e[t] = e;
        out_w[b * T + t] = e;   // unnormalized; finalize scales by 1/Z
    }
    __syncthreads();

    if (tid == 0) {
        float s = 0.f;
        for (int t = 0; t < tcut; ++t) s += sh_e[t];
        g_zinv[b] = 1.0f / (s + (float)(T - tcut));  // far field: e = 1 exactly
    }

    // correction vector: corr[e] = Sum_{t<tcut} (e_t - 1) * mem[b,t,e]
    {
        float c = 0.f;
        const float* mrow = memory + (size_t)b * T * E + tid;
        for (int t = 0; t < tcut; ++t) c += (sh_e[t] - 1.0f) * mrow[(size_t)t * E];
        g_corr[b * E + tid] = c;
    }
}

// ---------------------------------------------------------------------------
// K2: finalize. Grid B, 512 threads.
// ctx[b,e] = (Sum_partials + corr) * zinv ; out_w: e_t*zinv near, zinv far.
// ---------------------------------------------------------------------------
__global__ __launch_bounds__(512) void finalize_kernel(
    float* __restrict__ out_ctx,         // [B][E]
    float* __restrict__ out_w)           // [B][T]
{
    const int b = blockIdx.x;
    const int tid = threadIdx.x;
    const float inv = g_zinv[b];
    const int tcut = g_tcut[b];

    // context: thread tid owns element e = tid (E == 512)
    float acc = g_corr[b * E + tid];
    const float* p = g_partials + (size_t)b * NP * E + tid;
#pragma unroll 8
    for (int c = 0; c < NP; ++c) acc += p[(size_t)c * E];
    out_ctx[b * E + tid] = acc * inv;

    // attention weights
    for (int t = tid; t < T; t += 512) {
        out_w[b * T + t] = (t < tcut) ? out_w[b * T + t] * inv : inv;
    }
}

extern "C" void kernel_launch(void* const* d_in, const int* in_sizes, int n_in,
                              void* d_out, int out_size, void* d_ws, size_t ws_size,
                              hipStream_t stream) {
    const float* ahs      = (const float*)d_in[0];
    const float* memory   = (const float*)d_in[1];
    const float* prev_loc = (const float*)d_in[2];
    const unsigned char* mask = (const unsigned char*)d_in[3];
    const float* W1   = (const float*)d_in[4];
    const float* b1   = (const float*)d_in[5];
    const float* W2   = (const float*)d_in[6];
    const float* Wlin = (const float*)d_in[7];
    const float* blin = (const float*)d_in[8];

    float* out = (float*)d_out;
    float* out_ctx = out;                    // [B][E]
    float* out_w   = out + B * E;            // [B][T]
    float* out_loc = out + B * E + B * T;    // [B][M]

    (void)d_ws; (void)ws_size;  // scratch lives in __device__ globals

    fused_kernel<<<dim3(B + B * NCH), dim3(512), 0, stream>>>(
        ahs, prev_loc, mask, W1, b1, W2, Wlin, blin, memory, out_w, out_loc);

    finalize_kernel<<<dim3(B), dim3(512), 0, stream>>>(out_ctx, out_w);
}